// Round 1
// baseline (95.213 us; speedup 1.0000x reference)
//
#include <hip/hip_runtime.h>
#include <math.h>

// SIRD batched adaptive Tsit5 integrator.
// One thread per batch element; 31 intervals x <=12 adaptive steps, exactly
// mirroring the reference's masked-scan semantics (fresh t=t0 per interval,
// dt carried across intervals, done-cap at 12 steps).

#define PRED_LEN 32
#define MAX_STEPS 12

#define ATOL 1e-08f
#define RTOL 1e-04f
#define SAFETY 0.9f
#define MIN_FAC 0.2f
#define MAX_FAC 10.0f

#define A21 0.161f
#define A31 (-0.008480655492356989f)
#define A32 0.335480655492357f
#define A41 2.8971530571054935f
#define A42 (-6.359448489975075f)
#define A43 4.3622954328695815f
#define A51 5.325864828439257f
#define A52 (-11.748883564062828f)
#define A53 7.4955393428898365f
#define A54 (-0.09249506636175525f)
#define A61 5.86145544294642f
#define A62 (-12.92096931784711f)
#define A63 8.159367898576159f
#define A64 (-0.071584973281401f)
#define A65 (-0.028269050394068383f)
#define B1 0.09646076681806523f
#define B2 0.01f
#define B3 0.4798896504144996f
#define B4 1.379008574103742f
#define B5 (-3.290069515436081f)
#define B6 2.324710524099774f
#define E1 (-0.001780011052225777f)
#define E2 (-0.0008164344596567469f)
#define E3 0.007880878010261995f
#define E4 (-0.1447110071732629f)
#define E5 0.5823571654525552f
#define E6 (-0.45808210592918697f)
#define E7 0.015151515151515152f

__device__ __forceinline__ void rhs(const float y[4], float k[4],
                                    float binvN, float gm, float gamma, float mu) {
    float inf = binvN * y[0] * y[1];
    k[0] = -inf;
    k[1] = inf - gm * y[1];
    k[2] = gamma * y[1];
    k[3] = mu * y[1];
}

__global__ __launch_bounds__(256) void sird_tsit5_kernel(
    const float* __restrict__ x,    // [B,3] beta,gamma,mu
    const float* __restrict__ gp,   // [B,1]
    const float* __restrict__ pop,  // [B]
    float* __restrict__ out,        // [B,32,4]
    int B)
{
    int b = blockIdx.x * blockDim.x + threadIdx.x;
    if (b >= B) return;

    const float beta  = x[3 * b + 0];
    const float gamma = x[3 * b + 1];
    const float mu    = x[3 * b + 2];
    const float N     = pop[b];
    const float binvN = beta / N;   // beta*S*I/N computed as (beta/N)*S*I
    const float gm    = gamma + mu;

    float y[4];
    y[0] = gp[b] - 100.0f;   // S0
    y[1] = 100.0f;           // I0
    y[2] = 0.0f;             // R0
    y[3] = 0.0f;             // D0
    float dt = 0.05f;

    float4* o = (float4*)(out + (size_t)b * (PRED_LEN * 4));
    o[0] = make_float4(y[0], y[1], y[2], y[3]);

    float k1[4], k2[4], k3[4], k4[4], k5[4], k6[4], k7[4], yt[4], ynew[4];

    for (int seg = 0; seg < PRED_LEN - 1; ++seg) {
        const float t0 = (float)(32.0 * (double)seg / 31.0);
        const float t1 = (float)(32.0 * (double)(seg + 1) / 31.0);
        float t = t0;
        bool done = false;

        for (int s = 0; s < MAX_STEPS && !done; ++s) {
            const float h = fmaxf(fminf(dt, t1 - t), 1e-9f);

            rhs(y, k1, binvN, gm, gamma, mu);
#pragma unroll
            for (int c = 0; c < 4; ++c)
                yt[c] = fmaf(h, A21 * k1[c], y[c]);
            rhs(yt, k2, binvN, gm, gamma, mu);
#pragma unroll
            for (int c = 0; c < 4; ++c) {
                float a = fmaf(A32, k2[c], A31 * k1[c]);
                yt[c] = fmaf(h, a, y[c]);
            }
            rhs(yt, k3, binvN, gm, gamma, mu);
#pragma unroll
            for (int c = 0; c < 4; ++c) {
                float a = fmaf(A42, k2[c], A41 * k1[c]);
                a = fmaf(A43, k3[c], a);
                yt[c] = fmaf(h, a, y[c]);
            }
            rhs(yt, k4, binvN, gm, gamma, mu);
#pragma unroll
            for (int c = 0; c < 4; ++c) {
                float a = fmaf(A52, k2[c], A51 * k1[c]);
                a = fmaf(A53, k3[c], a);
                a = fmaf(A54, k4[c], a);
                yt[c] = fmaf(h, a, y[c]);
            }
            rhs(yt, k5, binvN, gm, gamma, mu);
#pragma unroll
            for (int c = 0; c < 4; ++c) {
                float a = fmaf(A62, k2[c], A61 * k1[c]);
                a = fmaf(A63, k3[c], a);
                a = fmaf(A64, k4[c], a);
                a = fmaf(A65, k5[c], a);
                yt[c] = fmaf(h, a, y[c]);
            }
            rhs(yt, k6, binvN, gm, gamma, mu);
#pragma unroll
            for (int c = 0; c < 4; ++c) {
                float a = fmaf(B2, k2[c], B1 * k1[c]);
                a = fmaf(B3, k3[c], a);
                a = fmaf(B4, k4[c], a);
                a = fmaf(B5, k5[c], a);
                a = fmaf(B6, k6[c], a);
                ynew[c] = fmaf(h, a, y[c]);
            }
            rhs(ynew, k7, binvN, gm, gamma, mu);

            float sumsq = 0.0f;
#pragma unroll
            for (int c = 0; c < 4; ++c) {
                float e = fmaf(E2, k2[c], E1 * k1[c]);
                e = fmaf(E3, k3[c], e);
                e = fmaf(E4, k4[c], e);
                e = fmaf(E5, k5[c], e);
                e = fmaf(E6, k6[c], e);
                e = fmaf(E7, k7[c], e);
                e = h * e;
                float tol = fmaf(RTOL, fmaxf(fabsf(y[c]), fabsf(ynew[c])), ATOL);
                float r = e / tol;
                sumsq = fmaf(r, r, sumsq);
            }
            const float enorm = sqrtf(0.25f * sumsq);

            const bool accept = (enorm <= 1.0f);
            const float en = (enorm > 0.0f) ? enorm : 1e-10f;
            float fac = SAFETY * powf(en, -0.2f);
            fac = fminf(fmaxf(fac, MIN_FAC), MAX_FAC);

            if (accept) {
                t += h;
#pragma unroll
                for (int c = 0; c < 4; ++c) y[c] = ynew[c];
            }
            dt = h * fac;                 // old `done` is false inside loop
            done = (t >= t1 - 1e-6f);
        }

        o[seg + 1] = make_float4(y[0], y[1], y[2], y[3]);
    }
}

extern "C" void kernel_launch(void* const* d_in, const int* in_sizes, int n_in,
                              void* d_out, int out_size, void* d_ws, size_t ws_size,
                              hipStream_t stream) {
    const float* x   = (const float*)d_in[0];
    const float* gp  = (const float*)d_in[1];
    const float* pop = (const float*)d_in[2];
    float* out = (float*)d_out;
    const int B = in_sizes[2];  // population is [B]

    const int block = 256;
    const int grid = (B + block - 1) / block;
    sird_tsit5_kernel<<<grid, block, 0, stream>>>(x, gp, pop, out, B);
}

// Round 3
// 79.219 us; speedup vs baseline: 1.2019x; 1.2019x over previous
//
#include <hip/hip_runtime.h>
#include <math.h>

// SIRD batched adaptive Tsit5 integrator — rank-2 RHS formulation.
// Every RHS vector k = inf*(-1,1,0,0) + I*(0,-(g+m),g,m), so each RK stage
// reduces to two scalar dot products (P over inf_j, Q over I_j) and only the
// (S,I) pair is propagated through stages; R,D materialize only at y_new.
// Transcendentals: v_log_f32 (log2) + v_exp_f32 (2^x) for the pow, v_rcp_f32
// for the tolerance divides. q = enorm^2 is used directly: enorm^-0.2 = q^-0.1.

#define PRED_LEN 32
#define MAX_STEPS 12

#define ATOL 1e-08f
#define RTOL 1e-04f

#define A21 0.161f
#define A31 (-0.008480655492356989f)
#define A32 0.335480655492357f
#define A41 2.8971530571054935f
#define A42 (-6.359448489975075f)
#define A43 4.3622954328695815f
#define A51 5.325864828439257f
#define A52 (-11.748883564062828f)
#define A53 7.4955393428898365f
#define A54 (-0.09249506636175525f)
#define A61 5.86145544294642f
#define A62 (-12.92096931784711f)
#define A63 8.159367898576159f
#define A64 (-0.071584973281401f)
#define A65 (-0.028269050394068383f)
#define B1 0.09646076681806523f
#define B2 0.01f
#define B3 0.4798896504144996f
#define B4 1.379008574103742f
#define B5 (-3.290069515436081f)
#define B6 2.324710524099774f
#define E1 (-0.001780011052225777f)
#define E2 (-0.0008164344596567469f)
#define E3 0.007880878010261995f
#define E4 (-0.1447110071732629f)
#define E5 0.5823571654525552f
#define E6 (-0.45808210592918697f)
#define E7 0.015151515151515152f

__global__ __launch_bounds__(256) void sird_tsit5_kernel(
    const float* __restrict__ x,    // [B,3] beta,gamma,mu
    const float* __restrict__ gp,   // [B,1]
    const float* __restrict__ pop,  // [B]
    float* __restrict__ out,        // [B,32,4]
    int B)
{
    int b = blockIdx.x * blockDim.x + threadIdx.x;
    if (b >= B) return;

    const float beta  = x[3 * b + 0];
    const float gamma = x[3 * b + 1];
    const float mu    = x[3 * b + 2];
    const float N     = pop[b];
    const float binvN = beta / N;     // beta*S*I/N == (beta/N)*S*I
    const float gm    = gamma + mu;

    float S = gp[b] - 100.0f;
    float I = 100.0f;
    float R = 0.0f;
    float D = 0.0f;
    float dt = 0.05f;

    float4* o = (float4*)(out + (size_t)b * (PRED_LEN * 4));
    o[0] = make_float4(S, I, R, D);

    for (int seg = 0; seg < PRED_LEN - 1; ++seg) {
        const float t0 = (float)(32.0 * (double)seg / 31.0);
        const float t1 = (float)(32.0 * (double)(seg + 1) / 31.0);
        float t = t0;
        bool done = false;

        for (int s = 0; s < MAX_STEPS && !done; ++s) {
            const float h = fmaxf(fminf(dt, t1 - t), 1e-9f);

            // ---- stage 1 (at y) ----
            const float inf1 = binvN * S * I;
            const float I1   = I;

            // ---- stage 2 ----
            float P = A21 * inf1;
            float Q = A21 * I1;
            float St = fmaf(-h, P, S);
            float It = fmaf(h, fmaf(-gm, Q, P), I);
            const float inf2 = binvN * St * It;
            const float I2   = It;

            // ---- stage 3 ----
            P = fmaf(A32, inf2, A31 * inf1);
            Q = fmaf(A32, I2,   A31 * I1);
            St = fmaf(-h, P, S);
            It = fmaf(h, fmaf(-gm, Q, P), I);
            const float inf3 = binvN * St * It;
            const float I3   = It;

            // ---- stage 4 ----
            P = fmaf(A43, inf3, fmaf(A42, inf2, A41 * inf1));
            Q = fmaf(A43, I3,   fmaf(A42, I2,   A41 * I1));
            St = fmaf(-h, P, S);
            It = fmaf(h, fmaf(-gm, Q, P), I);
            const float inf4 = binvN * St * It;
            const float I4   = It;

            // ---- stage 5 ----
            P = fmaf(A54, inf4, fmaf(A53, inf3, fmaf(A52, inf2, A51 * inf1)));
            Q = fmaf(A54, I4,   fmaf(A53, I3,   fmaf(A52, I2,   A51 * I1)));
            St = fmaf(-h, P, S);
            It = fmaf(h, fmaf(-gm, Q, P), I);
            const float inf5 = binvN * St * It;
            const float I5   = It;

            // ---- stage 6 ----
            P = fmaf(A65, inf5, fmaf(A64, inf4, fmaf(A63, inf3, fmaf(A62, inf2, A61 * inf1))));
            Q = fmaf(A65, I5,   fmaf(A64, I4,   fmaf(A63, I3,   fmaf(A62, I2,   A61 * I1))));
            St = fmaf(-h, P, S);
            It = fmaf(h, fmaf(-gm, Q, P), I);
            const float inf6 = binvN * St * It;
            const float I6   = It;

            // ---- y_new (b-weights, all 4 components) ----
            const float Pb = fmaf(B6, inf6, fmaf(B5, inf5, fmaf(B4, inf4, fmaf(B3, inf3, fmaf(B2, inf2, B1 * inf1)))));
            const float Qb = fmaf(B6, I6,   fmaf(B5, I5,   fmaf(B4, I4,   fmaf(B3, I3,   fmaf(B2, I2,   B1 * I1)))));
            const float hg = h * gamma;
            const float hm = h * mu;
            const float Sn = fmaf(-h, Pb, S);
            const float In = fmaf(h, fmaf(-gm, Qb, Pb), I);
            const float Rn = fmaf(hg, Qb, R);
            const float Dn = fmaf(hm, Qb, D);

            // ---- stage 7 (FSAL at y_new) ----
            const float inf7 = binvN * Sn * In;
            const float I7   = In;

            // ---- error (E-weights) ----
            const float Pe = fmaf(E7, inf7, fmaf(E6, inf6, fmaf(E5, inf5, fmaf(E4, inf4, fmaf(E3, inf3, fmaf(E2, inf2, E1 * inf1))))));
            const float Qe = fmaf(E7, I7,   fmaf(E6, I6,   fmaf(E5, I5,   fmaf(E4, I4,   fmaf(E3, I3,   fmaf(E2, I2,   E1 * I1))))));
            const float e0 = h * Pe;                    // sign irrelevant (squared)
            const float e1 = h * fmaf(-gm, Qe, Pe);
            const float e2 = hg * Qe;
            const float e3 = hm * Qe;

            const float tol0 = fmaf(RTOL, fmaxf(fabsf(S), fabsf(Sn)), ATOL);
            const float tol1 = fmaf(RTOL, fmaxf(fabsf(I), fabsf(In)), ATOL);
            const float tol2 = fmaf(RTOL, fmaxf(fabsf(R), fabsf(Rn)), ATOL);
            const float tol3 = fmaf(RTOL, fmaxf(fabsf(D), fabsf(Dn)), ATOL);

            const float r0 = e0 * __builtin_amdgcn_rcpf(tol0);
            const float r1 = e1 * __builtin_amdgcn_rcpf(tol1);
            const float r2 = e2 * __builtin_amdgcn_rcpf(tol2);
            const float r3 = e3 * __builtin_amdgcn_rcpf(tol3);

            float sumsq = r0 * r0;
            sumsq = fmaf(r1, r1, sumsq);
            sumsq = fmaf(r2, r2, sumsq);
            sumsq = fmaf(r3, r3, sumsq);
            const float q = 0.25f * sumsq;              // = enorm^2

            const bool accept = (q <= 1.0f);
            // fac = 0.9 * enorm^-0.2 = 0.9 * q^-0.1 = 0.9 * 2^(-0.1*log2(q))
            const float ql  = fmaxf(q, 1e-20f);
            float fac = 0.9f * __builtin_amdgcn_exp2f(-0.1f * __builtin_amdgcn_logf(ql));
            fac = fminf(fmaxf(fac, 0.2f), 10.0f);

            t = accept ? (t + h) : t;
            S = accept ? Sn : S;
            I = accept ? In : I;
            R = accept ? Rn : R;
            D = accept ? Dn : D;
            dt = h * fac;
            done = (t >= t1 - 1e-6f);
        }

        o[seg + 1] = make_float4(S, I, R, D);
    }
}

extern "C" void kernel_launch(void* const* d_in, const int* in_sizes, int n_in,
                              void* d_out, int out_size, void* d_ws, size_t ws_size,
                              hipStream_t stream) {
    const float* x   = (const float*)d_in[0];
    const float* gp  = (const float*)d_in[1];
    const float* pop = (const float*)d_in[2];
    float* out = (float*)d_out;
    const int B = in_sizes[2];  // population is [B]

    const int block = 256;
    const int grid = (B + block - 1) / block;
    sird_tsit5_kernel<<<grid, block, 0, stream>>>(x, gp, pop, out, B);
}

// Round 4
// 79.116 us; speedup vs baseline: 1.2034x; 1.0013x over previous
//
#include <hip/hip_runtime.h>
#include <math.h>

// SIRD batched adaptive Tsit5 — rank-2 RHS + fused interval/step loop.
// Each lane integrates continuously over t in [0,32], writing its output row
// when it crosses its own interval boundary (per-lane t1, per-lane 12-step
// cap). This converts wave time from sum-of-per-interval-maxes to
// max-of-total-steps across the 64 lanes (params are iid => big reduction).
// FSAL: stage-7 infection term is reused as next step's stage-1 term.

#define PRED_LEN 32
#define MAX_STEPS 12

#define ATOL 1e-08f
#define RTOL 1e-04f

#define A21 0.161f
#define A31 (-0.008480655492356989f)
#define A32 0.335480655492357f
#define A41 2.8971530571054935f
#define A42 (-6.359448489975075f)
#define A43 4.3622954328695815f
#define A51 5.325864828439257f
#define A52 (-11.748883564062828f)
#define A53 7.4955393428898365f
#define A54 (-0.09249506636175525f)
#define A61 5.86145544294642f
#define A62 (-12.92096931784711f)
#define A63 8.159367898576159f
#define A64 (-0.071584973281401f)
#define A65 (-0.028269050394068383f)
#define B1 0.09646076681806523f
#define B2 0.01f
#define B3 0.4798896504144996f
#define B4 1.379008574103742f
#define B5 (-3.290069515436081f)
#define B6 2.324710524099774f
#define E1 (-0.001780011052225777f)
#define E2 (-0.0008164344596567469f)
#define E3 0.007880878010261995f
#define E4 (-0.1447110071732629f)
#define E5 0.5823571654525552f
#define E6 (-0.45808210592918697f)
#define E7 0.015151515151515152f

__global__ __launch_bounds__(256) void sird_tsit5_kernel(
    const float* __restrict__ x,    // [B,3] beta,gamma,mu
    const float* __restrict__ gp,   // [B,1]
    const float* __restrict__ pop,  // [B]
    float* __restrict__ out,        // [B,32,4]
    int B)
{
    int b = blockIdx.x * blockDim.x + threadIdx.x;
    if (b >= B) return;

    const float beta  = x[3 * b + 0];
    const float gamma = x[3 * b + 1];
    const float mu    = x[3 * b + 2];
    const float N     = pop[b];
    const float binvN = beta / N;     // beta*S*I/N == (beta/N)*S*I
    const float gm    = gamma + mu;

    float S = gp[b] - 100.0f;
    float I = 100.0f;
    float R = 0.0f;
    float D = 0.0f;
    float dt = 0.05f;

    float4* o = (float4*)(out + (size_t)b * (PRED_LEN * 4));
    o[0] = make_float4(S, I, R, D);

    float inf1 = binvN * S * I;       // FSAL-carried stage-1 infection term
    float t  = 0.0f;
    float t1 = (float)(32.0 * 1.0 / 31.0);
    int seg  = 0;                     // current interval index [0,31)
    int scnt = 0;                     // steps taken in current interval

    while (seg < PRED_LEN - 1) {
        const float h = fmaxf(fminf(dt, t1 - t), 1e-9f);
        const float I1 = I;

        // ---- stage 2 ----
        float P = A21 * inf1;
        float Q = A21 * I1;
        float St = fmaf(-h, P, S);
        float It = fmaf(h, fmaf(-gm, Q, P), I);
        const float inf2 = (binvN * St) * It;
        const float I2   = It;

        // ---- stage 3 ----
        P = fmaf(A32, inf2, A31 * inf1);
        Q = fmaf(A32, I2,   A31 * I1);
        St = fmaf(-h, P, S);
        It = fmaf(h, fmaf(-gm, Q, P), I);
        const float inf3 = (binvN * St) * It;
        const float I3   = It;

        // ---- stage 4 ----
        P = fmaf(A43, inf3, fmaf(A42, inf2, A41 * inf1));
        Q = fmaf(A43, I3,   fmaf(A42, I2,   A41 * I1));
        St = fmaf(-h, P, S);
        It = fmaf(h, fmaf(-gm, Q, P), I);
        const float inf4 = (binvN * St) * It;
        const float I4   = It;

        // ---- stage 5 ----
        P = fmaf(A54, inf4, fmaf(A53, inf3, fmaf(A52, inf2, A51 * inf1)));
        Q = fmaf(A54, I4,   fmaf(A53, I3,   fmaf(A52, I2,   A51 * I1)));
        St = fmaf(-h, P, S);
        It = fmaf(h, fmaf(-gm, Q, P), I);
        const float inf5 = (binvN * St) * It;
        const float I5   = It;

        // ---- stage 6 ----
        P = fmaf(A65, inf5, fmaf(A64, inf4, fmaf(A63, inf3, fmaf(A62, inf2, A61 * inf1))));
        Q = fmaf(A65, I5,   fmaf(A64, I4,   fmaf(A63, I3,   fmaf(A62, I2,   A61 * I1))));
        St = fmaf(-h, P, S);
        It = fmaf(h, fmaf(-gm, Q, P), I);
        const float inf6 = (binvN * St) * It;
        const float I6   = It;

        // ---- y_new (b-weights) ----
        const float Pb = fmaf(B6, inf6, fmaf(B5, inf5, fmaf(B4, inf4, fmaf(B3, inf3, fmaf(B2, inf2, B1 * inf1)))));
        const float Qb = fmaf(B6, I6,   fmaf(B5, I5,   fmaf(B4, I4,   fmaf(B3, I3,   fmaf(B2, I2,   B1 * I1)))));
        const float hg = h * gamma;
        const float hm = h * mu;
        const float Sn = fmaf(-h, Pb, S);
        const float In = fmaf(h, fmaf(-gm, Qb, Pb), I);
        const float Rn = fmaf(hg, Qb, R);
        const float Dn = fmaf(hm, Qb, D);

        // ---- stage 7 (FSAL at y_new) ----
        const float inf7 = (binvN * Sn) * In;
        const float I7   = In;

        // ---- error (E-weights) ----
        const float Pe = fmaf(E7, inf7, fmaf(E6, inf6, fmaf(E5, inf5, fmaf(E4, inf4, fmaf(E3, inf3, fmaf(E2, inf2, E1 * inf1))))));
        const float Qe = fmaf(E7, I7,   fmaf(E6, I6,   fmaf(E5, I5,   fmaf(E4, I4,   fmaf(E3, I3,   fmaf(E2, I2,   E1 * I1))))));
        const float e0 = h * Pe;
        const float e1 = h * fmaf(-gm, Qe, Pe);
        const float e2 = hg * Qe;
        const float e3 = hm * Qe;

        const float tol0 = fmaf(RTOL, fmaxf(fabsf(S), fabsf(Sn)), ATOL);
        const float tol1 = fmaf(RTOL, fmaxf(fabsf(I), fabsf(In)), ATOL);
        const float tol2 = fmaf(RTOL, fmaxf(fabsf(R), fabsf(Rn)), ATOL);
        const float tol3 = fmaf(RTOL, fmaxf(fabsf(D), fabsf(Dn)), ATOL);

        const float r0 = e0 * __builtin_amdgcn_rcpf(tol0);
        const float r1 = e1 * __builtin_amdgcn_rcpf(tol1);
        const float r2 = e2 * __builtin_amdgcn_rcpf(tol2);
        const float r3 = e3 * __builtin_amdgcn_rcpf(tol3);

        float sumsq = r0 * r0;
        sumsq = fmaf(r1, r1, sumsq);
        sumsq = fmaf(r2, r2, sumsq);
        sumsq = fmaf(r3, r3, sumsq);
        const float q = 0.25f * sumsq;            // = enorm^2

        // fac = 0.9 * enorm^-0.2 = 0.9 * 2^(-0.1*log2(q)), q clamped like ref
        const float ql = fmaxf(q, 1e-20f);
        float fac = 0.9f * __builtin_amdgcn_exp2f(-0.1f * __builtin_amdgcn_logf(ql));
        fac = fminf(fmaxf(fac, 0.2f), 10.0f);

        const bool accept = (q <= 1.0f);
        t    = accept ? (t + h) : t;
        S    = accept ? Sn : S;
        I    = accept ? In : I;
        R    = accept ? Rn : R;
        D    = accept ? Dn : D;
        inf1 = accept ? inf7 : inf1;   // FSAL: y unchanged on reject => inf1 unchanged
        dt = h * fac;
        ++scnt;

        if ((t >= t1 - 1e-6f) || (scnt >= MAX_STEPS)) {
            o[seg + 1] = make_float4(S, I, R, D);
            ++seg;
            scnt = 0;
            t  = (float)(32.0 * (double)seg / 31.0);
            t1 = (float)(32.0 * (double)(seg + 1) / 31.0);
        }
    }
}

extern "C" void kernel_launch(void* const* d_in, const int* in_sizes, int n_in,
                              void* d_out, int out_size, void* d_ws, size_t ws_size,
                              hipStream_t stream) {
    const float* x   = (const float*)d_in[0];
    const float* gp  = (const float*)d_in[1];
    const float* pop = (const float*)d_in[2];
    float* out = (float*)d_out;
    const int B = in_sizes[2];  // population is [B]

    const int block = 256;
    const int grid = (B + block - 1) / block;
    sird_tsit5_kernel<<<grid, block, 0, stream>>>(x, gp, pop, out, B);
}